// Round 3
// baseline (383.850 us; speedup 1.0000x reference)
//
#include <hip/hip_runtime.h>

#define HW 160000   // 400*400
#define WIMG 400

// -------------------------------------------------------------------------
// conv1: x[B,3,400,400] -> leaky(conv 3->6, k3 s2 p1) restricted to out
// region [0..63]^2 (receptive field of the palette 4x4).
// out: c1[B,6,64,64]. 16*6*64*64 = 393216 threads.
// -------------------------------------------------------------------------
__global__ __launch_bounds__(256) void conv1_k(const float* __restrict__ x,
                                               const float* __restrict__ w,
                                               const float* __restrict__ bias,
                                               float* __restrict__ out) {
  int idx = blockIdx.x * 256 + threadIdx.x;
  int j = idx & 63;
  int i = (idx >> 6) & 63;
  int t = idx >> 12;
  int o = t % 6;
  int b = t / 6;
  float acc = bias[o];
#pragma unroll
  for (int c = 0; c < 3; c++) {
    const float* xc = x + (size_t)(b * 3 + c) * HW;
    const float* wc = w + (o * 3 + c) * 9;
#pragma unroll
    for (int di = 0; di < 3; di++) {
      int xi = 2 * i - 1 + di;
      if (xi < 0) continue;
#pragma unroll
      for (int dj = 0; dj < 3; dj++) {
        int xj = 2 * j - 1 + dj;
        if (xj < 0) continue;
        acc = fmaf(xc[xi * WIMG + xj], wc[di * 3 + dj], acc);
      }
    }
  }
  out[idx] = acc >= 0.f ? acc : 0.01f * acc;
}

// conv2: c1[B,6,64,64] -> leaky(conv 6->12 s2 p1) = c2[B,12,32,32].
// Flat one-thread-per-output. 16*12*32*32 = 196608 threads.
__global__ __launch_bounds__(256) void conv2_k(const float* __restrict__ in,
                                               const float* __restrict__ w,
                                               const float* __restrict__ bias,
                                               float* __restrict__ out) {
  int idx = blockIdx.x * 256 + threadIdx.x;
  int j = idx & 31;
  int i = (idx >> 5) & 31;
  int t = idx >> 10;
  int o = t % 12;
  int b = t / 12;
  float acc = bias[o];
#pragma unroll
  for (int c = 0; c < 6; c++) {
    const float* xc = in + (size_t)(b * 6 + c) * 4096;
    const float* wc = w + (o * 6 + c) * 9;
#pragma unroll
    for (int di = 0; di < 3; di++) {
      int xi = 2 * i - 1 + di;
      if (xi < 0) continue;
#pragma unroll
      for (int dj = 0; dj < 3; dj++) {
        int xj = 2 * j - 1 + dj;
        if (xj < 0) continue;
        acc = fmaf(xc[xi * 64 + xj], wc[di * 3 + dj], acc);
      }
    }
  }
  out[idx] = acc >= 0.f ? acc : 0.01f * acc;
}

// -------------------------------------------------------------------------
// conv3..conv6 fused, one block per batch, intermediates in LDS.
// Stage c2[b] (48KB) -> conv3 12x16x16 -> conv4 12x8x8 -> conv5 6x4x4 ->
// conv6 1x1 relu -> pal[b,3,16]. Logic identical to verified round-1 tail.
// -------------------------------------------------------------------------
__global__ __launch_bounds__(256) void conv3456_k(
    const float* __restrict__ c2, const float* __restrict__ w3,
    const float* __restrict__ b3, const float* __restrict__ w4,
    const float* __restrict__ b4, const float* __restrict__ w5,
    const float* __restrict__ b5, const float* __restrict__ w6,
    const float* __restrict__ b6, float* __restrict__ pal) {
  __shared__ float s[12288];   // c2 tile; later reused for conv4/conv5 out
  __shared__ float o3[3072];   // conv3 out 12x16x16
  int tid = threadIdx.x;
  int b = blockIdx.x;

  for (int t = tid; t < 12288; t += 256) s[t] = c2[(size_t)b * 12288 + t];
  __syncthreads();

  // conv3: 12x16x16
#pragma unroll
  for (int r = 0; r < 12; r++) {
    int idx = tid + 256 * r;
    int j = idx & 15, i = (idx >> 4) & 15, o = idx >> 8;
    float a = b3[o];
    for (int c = 0; c < 12; c++) {
      const float* wc = w3 + (o * 12 + c) * 9;
      const float* sc = s + c * 1024;
#pragma unroll
      for (int di = 0; di < 3; di++) {
        int xi = 2 * i - 1 + di;
        if (xi < 0) continue;
#pragma unroll
        for (int dj = 0; dj < 3; dj++) {
          int xj = 2 * j - 1 + dj;
          if (xj < 0) continue;
          a = fmaf(sc[xi * 32 + xj], wc[di * 3 + dj], a);
        }
      }
    }
    o3[idx] = a >= 0.f ? a : 0.01f * a;
  }
  __syncthreads();

  // conv4: 12x8x8 -> s[0..768)
#pragma unroll
  for (int r = 0; r < 3; r++) {
    int idx = tid + 256 * r;
    int j = idx & 7, i = (idx >> 3) & 7, o = idx >> 6;
    float a = b4[o];
    for (int c = 0; c < 12; c++) {
      const float* wc = w4 + (o * 12 + c) * 9;
      const float* sc = o3 + c * 256;
#pragma unroll
      for (int di = 0; di < 3; di++) {
        int xi = 2 * i - 1 + di;
        if (xi < 0) continue;
#pragma unroll
        for (int dj = 0; dj < 3; dj++) {
          int xj = 2 * j - 1 + dj;
          if (xj < 0) continue;
          a = fmaf(sc[xi * 16 + xj], wc[di * 3 + dj], a);
        }
      }
    }
    __syncthreads();  // ensure all conv4 reads of s are not needed... (s written below)
    s[idx] = a >= 0.f ? a : 0.01f * a;
  }
  __syncthreads();

  // conv5: 6x4x4 -> s[1024..1120)  (reads s[0..768), writes disjoint region)
  if (tid < 96) {
    int j = tid & 3, i = (tid >> 2) & 3, o = tid >> 4;
    float a = b5[o];
    for (int c = 0; c < 12; c++) {
      const float* wc = w5 + (o * 12 + c) * 9;
      const float* sc = s + c * 64;
#pragma unroll
      for (int di = 0; di < 3; di++) {
        int xi = 2 * i - 1 + di;
        if (xi < 0) continue;
#pragma unroll
        for (int dj = 0; dj < 3; dj++) {
          int xj = 2 * j - 1 + dj;
          if (xj < 0) continue;
          a = fmaf(sc[xi * 8 + xj], wc[di * 3 + dj], a);
        }
      }
    }
    s[1024 + tid] = a >= 0.f ? a : 0.01f * a;  // layout o*16 + (i*4+j)
  }
  __syncthreads();

  // conv6 (1x1) + relu -> pal[b,3,16]
  if (tid < 48) {
    int k = tid & 15, o = tid >> 4;
    float a = b6[o];
#pragma unroll
    for (int c = 0; c < 6; c++) a = fmaf(s[1024 + c * 16 + k], w6[o * 6 + c], a);
    pal[b * 48 + o * 16 + k] = a > 0.f ? a : 0.f;
  }
}

// -------------------------------------------------------------------------
// gather: all 16 channel float4 loads hoisted into registers (16 outstanding
// 1KB-per-wave loads -> latency covered), then streaming argmax tie-sum:
// greater -> reset RGB to pal[k]; equal -> add pal[k]. Exactly reproduces
// the reference (probs==max) one-hot-with-ties contraction (softmax is
// monotone; prob ties <=> bitwise-equal fp32 logits).
// -------------------------------------------------------------------------
__global__ __launch_bounds__(256) void gather_k(const float* __restrict__ logits,
                                                const float* __restrict__ pal,
                                                float* __restrict__ out) {
  __shared__ float ps[48];
  int b = blockIdx.y;
  int tid = threadIdx.x;
  if (tid < 48) ps[tid] = pal[b * 48 + tid];
  __syncthreads();
  int q = blockIdx.x * 256 + tid;
  if (q >= HW / 4) return;
  const float* lg = logits + (size_t)b * 16 * HW + q * 4;

  float4 t[16];
#pragma unroll
  for (int k = 0; k < 16; k++) t[k] = *(const float4*)(lg + (size_t)k * HW);

  float mx[4] = {t[0].x, t[0].y, t[0].z, t[0].w};
  float p0 = ps[0], p1 = ps[16], p2 = ps[32];
  float r0[4] = {p0, p0, p0, p0};
  float r1[4] = {p1, p1, p1, p1};
  float r2[4] = {p2, p2, p2, p2};

#pragma unroll
  for (int k = 1; k < 16; k++) {
    float q0 = ps[k], q1 = ps[16 + k], q2 = ps[32 + k];
    float vv[4] = {t[k].x, t[k].y, t[k].z, t[k].w};
#pragma unroll
    for (int pp = 0; pp < 4; pp++) {
      float val = vv[pp];
      bool gt = val > mx[pp];
      bool ge = val >= mx[pp];
      mx[pp] = ge ? val : mx[pp];
      r0[pp] = (gt ? 0.f : r0[pp]) + (ge ? q0 : 0.f);
      r1[pp] = (gt ? 0.f : r1[pp]) + (ge ? q1 : 0.f);
      r2[pp] = (gt ? 0.f : r2[pp]) + (ge ? q2 : 0.f);
    }
  }
  float* ob = out + (size_t)b * 3 * HW + q * 4;
  *(float4*)(ob) = make_float4(r0[0], r0[1], r0[2], r0[3]);
  *(float4*)(ob + HW) = make_float4(r1[0], r1[1], r1[2], r1[3]);
  *(float4*)(ob + 2 * HW) = make_float4(r2[0], r2[1], r2[2], r2[3]);
}

extern "C" void kernel_launch(void* const* d_in, const int* in_sizes, int n_in,
                              void* d_out, int out_size, void* d_ws, size_t ws_size,
                              hipStream_t stream) {
  const float* x    = (const float*)d_in[0];
  const float* blog = (const float*)d_in[1];
  const float* w1 = (const float*)d_in[2];
  const float* b1 = (const float*)d_in[3];
  const float* w2 = (const float*)d_in[4];
  const float* b2 = (const float*)d_in[5];
  const float* w3 = (const float*)d_in[6];
  const float* b3 = (const float*)d_in[7];
  const float* w4 = (const float*)d_in[8];
  const float* b4 = (const float*)d_in[9];
  const float* w5 = (const float*)d_in[10];
  const float* b5 = (const float*)d_in[11];
  const float* w6 = (const float*)d_in[12];
  const float* b6 = (const float*)d_in[13];
  float* out = (float*)d_out;

  float* c1  = (float*)d_ws;            // [16,6,64,64]  393216
  float* c2  = c1 + 16 * 6 * 64 * 64;   // [16,12,32,32] 196608
  float* pal = c2 + 16 * 12 * 32 * 32;  // [16,3,16]     768

  conv1_k<<<1536, 256, 0, stream>>>(x, w1, b1, c1);
  conv2_k<<<768, 256, 0, stream>>>(c1, w2, b2, c2);
  conv3456_k<<<16, 256, 0, stream>>>(c2, w3, b3, w4, b4, w5, b5, w6, b6, pal);
  gather_k<<<dim3((HW / 4 + 255) / 256, 16), 256, 0, stream>>>(blog, pal, out);
}

// Round 4
// 327.769 us; speedup vs baseline: 1.1711x; 1.1711x over previous
//
#include <hip/hip_runtime.h>

#define HW 160000   // 400*400
#define WIMG 400

typedef float v4 __attribute__((ext_vector_type(4)));

// -------------------------------------------------------------------------
// conv1: x[B,3,400,400] -> leaky(conv 3->6, k3 s2 p1) restricted to out
// region [0..63]^2 (receptive field of the palette 4x4).
// out: c1[B,6,64,64]. 16*6*64*64 = 393216 threads. [R2-verified]
// -------------------------------------------------------------------------
__global__ __launch_bounds__(256) void conv1_k(const float* __restrict__ x,
                                               const float* __restrict__ w,
                                               const float* __restrict__ bias,
                                               float* __restrict__ out) {
  int idx = blockIdx.x * 256 + threadIdx.x;
  int j = idx & 63;
  int i = (idx >> 6) & 63;
  int t = idx >> 12;
  int o = t % 6;
  int b = t / 6;
  float acc = bias[o];
#pragma unroll
  for (int c = 0; c < 3; c++) {
    const float* xc = x + (size_t)(b * 3 + c) * HW;
    const float* wc = w + (o * 3 + c) * 9;
#pragma unroll
    for (int di = 0; di < 3; di++) {
      int xi = 2 * i - 1 + di;
      if (xi < 0) continue;
#pragma unroll
      for (int dj = 0; dj < 3; dj++) {
        int xj = 2 * j - 1 + dj;
        if (xj < 0) continue;
        acc = fmaf(xc[xi * WIMG + xj], wc[di * 3 + dj], acc);
      }
    }
  }
  out[idx] = acc >= 0.f ? acc : 0.01f * acc;
}

// Generic strided 3x3 s2 p1 conv + leaky, flat-parallel, one thread/output.
// N = output spatial dim (input is 2N x 2N), CIN input channels. [R2-verified]
template <int N, int CIN>
__global__ __launch_bounds__(256) void convs_k(const float* __restrict__ in,
                                               const float* __restrict__ w,
                                               const float* __restrict__ bias,
                                               float* __restrict__ out,
                                               int cout) {
  int idx = blockIdx.x * 256 + threadIdx.x;
  int j = idx & (N - 1);
  int i = (idx / N) & (N - 1);
  int t = idx / (N * N);
  int o = t % cout;
  int b = t / cout;
  float acc = bias[o];
#pragma unroll
  for (int c = 0; c < CIN; c++) {
    const float* xc = in + (size_t)(b * CIN + c) * (4 * N * N);
    const float* wc = w + (o * CIN + c) * 9;
#pragma unroll
    for (int di = 0; di < 3; di++) {
      int xi = 2 * i - 1 + di;
      if (xi < 0) continue;
#pragma unroll
      for (int dj = 0; dj < 3; dj++) {
        int xj = 2 * j - 1 + dj;
        if (xj < 0) continue;
        acc = fmaf(xc[xi * 2 * N + xj], wc[di * 3 + dj], acc);
      }
    }
  }
  out[idx] = acc >= 0.f ? acc : 0.01f * acc;
}

// conv6: 1x1, 6->3, relu. in c5[B,6,4,4]; out pal[B,3,16]. [R2-verified]
__global__ __launch_bounds__(256) void conv6_k(const float* __restrict__ c5,
                                               const float* __restrict__ w,
                                               const float* __restrict__ bias,
                                               float* __restrict__ pal) {
  int idx = blockIdx.x * 256 + threadIdx.x;
  int k = idx & 15;
  int t = idx >> 4;
  int o = t % 3;
  int b = t / 3;
  float a = bias[o];
#pragma unroll
  for (int c = 0; c < 6; c++) a = fmaf(c5[b * 96 + c * 16 + k], w[o * 6 + c], a);
  pal[b * 48 + o * 16 + k] = a > 0.f ? a : 0.f;
}

// -------------------------------------------------------------------------
// gather: 8 px/thread, interleaved (low-VGPR) streaming argmax tie-sum:
// greater -> reset RGB to pal[k]; equal -> add pal[k]. Exactly reproduces
// the reference (probs==max) one-hot-with-ties contraction (softmax is
// monotone; prob ties <=> bitwise-equal fp32 logits). Nontemporal loads/
// stores: logits and out are single-touch streams, keep them out of L2/L3.
// -------------------------------------------------------------------------
__global__ __launch_bounds__(256) void gather_k(const float* __restrict__ logits,
                                                const float* __restrict__ pal,
                                                float* __restrict__ out) {
  __shared__ float ps[48];
  int b = blockIdx.y;
  int tid = threadIdx.x;
  if (tid < 48) ps[tid] = pal[b * 48 + tid];
  __syncthreads();
  int q = blockIdx.x * 256 + tid;
  if (q >= HW / 8) return;
  const float* lg = logits + (size_t)b * 16 * HW + q * 8;

  v4 t0 = __builtin_nontemporal_load((const v4*)lg);
  v4 t1 = __builtin_nontemporal_load((const v4*)(lg + 4));
  float mx[8] = {t0.x, t0.y, t0.z, t0.w, t1.x, t1.y, t1.z, t1.w};
  float p0 = ps[0], p1 = ps[16], p2 = ps[32];
  float r0[8], r1[8], r2[8];
#pragma unroll
  for (int pp = 0; pp < 8; pp++) { r0[pp] = p0; r1[pp] = p1; r2[pp] = p2; }

#pragma unroll
  for (int k = 1; k < 16; k++) {
    const float* lk = lg + (size_t)k * HW;
    v4 a0 = __builtin_nontemporal_load((const v4*)lk);
    v4 a1 = __builtin_nontemporal_load((const v4*)(lk + 4));
    float vv[8] = {a0.x, a0.y, a0.z, a0.w, a1.x, a1.y, a1.z, a1.w};
    float q0 = ps[k], q1 = ps[16 + k], q2 = ps[32 + k];
#pragma unroll
    for (int pp = 0; pp < 8; pp++) {
      float val = vv[pp];
      bool gt = val > mx[pp];
      bool ge = val >= mx[pp];
      mx[pp] = ge ? val : mx[pp];
      r0[pp] = (gt ? 0.f : r0[pp]) + (ge ? q0 : 0.f);
      r1[pp] = (gt ? 0.f : r1[pp]) + (ge ? q1 : 0.f);
      r2[pp] = (gt ? 0.f : r2[pp]) + (ge ? q2 : 0.f);
    }
  }
  float* ob = out + (size_t)b * 3 * HW + q * 8;
  v4 s0 = {r0[0], r0[1], r0[2], r0[3]}, s1 = {r0[4], r0[5], r0[6], r0[7]};
  __builtin_nontemporal_store(s0, (v4*)ob);
  __builtin_nontemporal_store(s1, (v4*)(ob + 4));
  v4 s2 = {r1[0], r1[1], r1[2], r1[3]}, s3 = {r1[4], r1[5], r1[6], r1[7]};
  __builtin_nontemporal_store(s2, (v4*)(ob + HW));
  __builtin_nontemporal_store(s3, (v4*)(ob + HW + 4));
  v4 s4 = {r2[0], r2[1], r2[2], r2[3]}, s5 = {r2[4], r2[5], r2[6], r2[7]};
  __builtin_nontemporal_store(s4, (v4*)(ob + 2 * HW));
  __builtin_nontemporal_store(s5, (v4*)(ob + 2 * HW + 4));
}

extern "C" void kernel_launch(void* const* d_in, const int* in_sizes, int n_in,
                              void* d_out, int out_size, void* d_ws, size_t ws_size,
                              hipStream_t stream) {
  const float* x    = (const float*)d_in[0];
  const float* blog = (const float*)d_in[1];
  const float* w1 = (const float*)d_in[2];
  const float* b1 = (const float*)d_in[3];
  const float* w2 = (const float*)d_in[4];
  const float* b2 = (const float*)d_in[5];
  const float* w3 = (const float*)d_in[6];
  const float* b3 = (const float*)d_in[7];
  const float* w4 = (const float*)d_in[8];
  const float* b4 = (const float*)d_in[9];
  const float* w5 = (const float*)d_in[10];
  const float* b5 = (const float*)d_in[11];
  const float* w6 = (const float*)d_in[12];
  const float* b6 = (const float*)d_in[13];
  float* out = (float*)d_out;

  float* c1  = (float*)d_ws;            // [16,6,64,64]  393216
  float* c2  = c1 + 16 * 6 * 64 * 64;   // [16,12,32,32] 196608
  float* c3  = c2 + 16 * 12 * 32 * 32;  // [16,12,16,16] 49152
  float* c4  = c3 + 16 * 12 * 16 * 16;  // [16,12,8,8]   12288
  float* c5  = c4 + 16 * 12 * 8 * 8;    // [16,6,4,4]    1536
  float* pal = c5 + 16 * 6 * 4 * 4;     // [16,3,16]     768

  conv1_k<<<1536, 256, 0, stream>>>(x, w1, b1, c1);
  convs_k<32, 6><<<768, 256, 0, stream>>>(c1, w2, b2, c2, 12);
  convs_k<16, 12><<<192, 256, 0, stream>>>(c2, w3, b3, c3, 12);
  convs_k<8, 12><<<48, 256, 0, stream>>>(c3, w4, b4, c4, 12);
  convs_k<4, 12><<<6, 256, 0, stream>>>(c4, w5, b5, c5, 6);
  conv6_k<<<3, 256, 0, stream>>>(c5, w6, b6, pal);
  gather_k<<<dim3((HW / 8 + 255) / 256, 16), 256, 0, stream>>>(blog, pal, out);
}

// Round 5
// 327.438 us; speedup vs baseline: 1.1723x; 1.0010x over previous
//
#include <hip/hip_runtime.h>

#define HW 160000   // 400*400
#define WIMG 400

typedef float v4 __attribute__((ext_vector_type(4)));

// -------------------------------------------------------------------------
// conv1: x[B,3,400,400] -> leaky(conv 3->6, k3 s2 p1) restricted to out
// region [0..63]^2 (receptive field of the palette 4x4).
// out: c1[B,6,64,64]. 16*6*64*64 = 393216 threads. [verified R2/R4]
// -------------------------------------------------------------------------
__global__ __launch_bounds__(256) void conv1_k(const float* __restrict__ x,
                                               const float* __restrict__ w,
                                               const float* __restrict__ bias,
                                               float* __restrict__ out) {
  int idx = blockIdx.x * 256 + threadIdx.x;
  int j = idx & 63;
  int i = (idx >> 6) & 63;
  int t = idx >> 12;
  int o = t % 6;
  int b = t / 6;
  float acc = bias[o];
#pragma unroll
  for (int c = 0; c < 3; c++) {
    const float* xc = x + (size_t)(b * 3 + c) * HW;
    const float* wc = w + (o * 3 + c) * 9;
#pragma unroll
    for (int di = 0; di < 3; di++) {
      int xi = 2 * i - 1 + di;
      if (xi < 0) continue;
#pragma unroll
      for (int dj = 0; dj < 3; dj++) {
        int xj = 2 * j - 1 + dj;
        if (xj < 0) continue;
        acc = fmaf(xc[xi * WIMG + xj], wc[di * 3 + dj], acc);
      }
    }
  }
  out[idx] = acc >= 0.f ? acc : 0.01f * acc;
}

// Generic strided 3x3 s2 p1 conv + leaky, flat-parallel, one thread/output.
// N = output spatial dim (input is 2N x 2N), CIN input channels. [verified]
template <int N, int CIN>
__global__ __launch_bounds__(256) void convs_k(const float* __restrict__ in,
                                               const float* __restrict__ w,
                                               const float* __restrict__ bias,
                                               float* __restrict__ out,
                                               int cout) {
  int idx = blockIdx.x * 256 + threadIdx.x;
  int j = idx & (N - 1);
  int i = (idx / N) & (N - 1);
  int t = idx / (N * N);
  int o = t % cout;
  int b = t / cout;
  float acc = bias[o];
#pragma unroll
  for (int c = 0; c < CIN; c++) {
    const float* xc = in + (size_t)(b * CIN + c) * (4 * N * N);
    const float* wc = w + (o * CIN + c) * 9;
#pragma unroll
    for (int di = 0; di < 3; di++) {
      int xi = 2 * i - 1 + di;
      if (xi < 0) continue;
#pragma unroll
      for (int dj = 0; dj < 3; dj++) {
        int xj = 2 * j - 1 + dj;
        if (xj < 0) continue;
        acc = fmaf(xc[xi * 2 * N + xj], wc[di * 3 + dj], acc);
      }
    }
  }
  out[idx] = acc >= 0.f ? acc : 0.01f * acc;
}

// -------------------------------------------------------------------------
// conv4+conv5+conv6 fused, one block per batch (these stages are tiny --
// the R3 serialization disease came from conv3, which stays flat).
// in c3[B,12,16,16]; stages in LDS; out pal[B,3,16]. Stage logic identical
// to the R1-verified tail.
// -------------------------------------------------------------------------
__global__ __launch_bounds__(256) void conv456_k(
    const float* __restrict__ c3, const float* __restrict__ w4,
    const float* __restrict__ b4, const float* __restrict__ w5,
    const float* __restrict__ b5, const float* __restrict__ w6,
    const float* __restrict__ b6, float* __restrict__ pal) {
  __shared__ float s4[768];  // conv4 out: 12ch x 8x8
  __shared__ float s5[96];   // conv5 out: 6ch x 4x4, layout o*16 + (i*4+j)
  int tid = threadIdx.x;
  int b = blockIdx.x;
  const float* cb = c3 + (size_t)b * 12 * 256;

  // conv4: 12x8x8, 3 outputs/thread, input from global (L2-hot)
#pragma unroll
  for (int r = 0; r < 3; r++) {
    int idx = tid + 256 * r;
    int j = idx & 7, i = (idx >> 3) & 7, o = idx >> 6;
    float a = b4[o];
    for (int c = 0; c < 12; c++) {
      const float* wc = w4 + (o * 12 + c) * 9;
      const float* sc = cb + c * 256;
#pragma unroll
      for (int di = 0; di < 3; di++) {
        int xi = 2 * i - 1 + di;
        if (xi < 0) continue;
#pragma unroll
        for (int dj = 0; dj < 3; dj++) {
          int xj = 2 * j - 1 + dj;
          if (xj < 0) continue;
          a = fmaf(sc[xi * 16 + xj], wc[di * 3 + dj], a);
        }
      }
    }
    s4[idx] = a >= 0.f ? a : 0.01f * a;
  }
  __syncthreads();

  // conv5: 6x4x4 on 96 threads
  if (tid < 96) {
    int j = tid & 3, i = (tid >> 2) & 3, o = tid >> 4;
    float a = b5[o];
    for (int c = 0; c < 12; c++) {
      const float* wc = w5 + (o * 12 + c) * 9;
      const float* sc = s4 + c * 64;
#pragma unroll
      for (int di = 0; di < 3; di++) {
        int xi = 2 * i - 1 + di;
        if (xi < 0) continue;
#pragma unroll
        for (int dj = 0; dj < 3; dj++) {
          int xj = 2 * j - 1 + dj;
          if (xj < 0) continue;
          a = fmaf(sc[xi * 8 + xj], wc[di * 3 + dj], a);
        }
      }
    }
    s5[tid] = a >= 0.f ? a : 0.01f * a;
  }
  __syncthreads();

  // conv6 (1x1) + relu -> pal[b,3,16]
  if (tid < 48) {
    int k = tid & 15, o = tid >> 4;
    float a = b6[o];
#pragma unroll
    for (int c = 0; c < 6; c++) a = fmaf(s5[c * 16 + k], w6[o * 6 + c], a);
    pal[b * 48 + o * 16 + k] = a > 0.f ? a : 0.f;
  }
}

// -------------------------------------------------------------------------
// gather: 4 px/thread; ALL 16 channel float4 loads hoisted (measured: the
// hoisted form keeps 16 loads in flight -> 45us vs 92us interleaved), with
// nontemporal loads/stores (single-touch streams, measured -8.8us). Then
// streaming argmax tie-sum: greater -> reset RGB to pal[k]; equal -> add
// pal[k]. Exactly reproduces the reference (probs==max) one-hot-with-ties
// contraction (softmax monotone; prob ties <=> bitwise-equal fp32 logits).
// -------------------------------------------------------------------------
__global__ __launch_bounds__(256) void gather_k(const float* __restrict__ logits,
                                                const float* __restrict__ pal,
                                                float* __restrict__ out) {
  __shared__ float ps[48];
  int b = blockIdx.y;
  int tid = threadIdx.x;
  if (tid < 48) ps[tid] = pal[b * 48 + tid];
  __syncthreads();
  int q = blockIdx.x * 256 + tid;
  if (q >= HW / 4) return;
  const float* lg = logits + (size_t)b * 16 * HW + q * 4;

  v4 t[16];
#pragma unroll
  for (int k = 0; k < 16; k++)
    t[k] = __builtin_nontemporal_load((const v4*)(lg + (size_t)k * HW));

  float mx[4] = {t[0].x, t[0].y, t[0].z, t[0].w};
  float p0 = ps[0], p1 = ps[16], p2 = ps[32];
  float r0[4] = {p0, p0, p0, p0};
  float r1[4] = {p1, p1, p1, p1};
  float r2[4] = {p2, p2, p2, p2};

#pragma unroll
  for (int k = 1; k < 16; k++) {
    float q0 = ps[k], q1 = ps[16 + k], q2 = ps[32 + k];
    float vv[4] = {t[k].x, t[k].y, t[k].z, t[k].w};
#pragma unroll
    for (int pp = 0; pp < 4; pp++) {
      float val = vv[pp];
      bool gt = val > mx[pp];
      bool ge = val >= mx[pp];
      mx[pp] = ge ? val : mx[pp];
      r0[pp] = (gt ? 0.f : r0[pp]) + (ge ? q0 : 0.f);
      r1[pp] = (gt ? 0.f : r1[pp]) + (ge ? q1 : 0.f);
      r2[pp] = (gt ? 0.f : r2[pp]) + (ge ? q2 : 0.f);
    }
  }
  float* ob = out + (size_t)b * 3 * HW + q * 4;
  v4 s0 = {r0[0], r0[1], r0[2], r0[3]};
  v4 s1 = {r1[0], r1[1], r1[2], r1[3]};
  v4 s2 = {r2[0], r2[1], r2[2], r2[3]};
  __builtin_nontemporal_store(s0, (v4*)ob);
  __builtin_nontemporal_store(s1, (v4*)(ob + HW));
  __builtin_nontemporal_store(s2, (v4*)(ob + 2 * HW));
}

extern "C" void kernel_launch(void* const* d_in, const int* in_sizes, int n_in,
                              void* d_out, int out_size, void* d_ws, size_t ws_size,
                              hipStream_t stream) {
  const float* x    = (const float*)d_in[0];
  const float* blog = (const float*)d_in[1];
  const float* w1 = (const float*)d_in[2];
  const float* b1 = (const float*)d_in[3];
  const float* w2 = (const float*)d_in[4];
  const float* b2 = (const float*)d_in[5];
  const float* w3 = (const float*)d_in[6];
  const float* b3 = (const float*)d_in[7];
  const float* w4 = (const float*)d_in[8];
  const float* b4 = (const float*)d_in[9];
  const float* w5 = (const float*)d_in[10];
  const float* b5 = (const float*)d_in[11];
  const float* w6 = (const float*)d_in[12];
  const float* b6 = (const float*)d_in[13];
  float* out = (float*)d_out;

  float* c1  = (float*)d_ws;            // [16,6,64,64]  393216
  float* c2  = c1 + 16 * 6 * 64 * 64;   // [16,12,32,32] 196608
  float* c3  = c2 + 16 * 12 * 32 * 32;  // [16,12,16,16] 49152
  float* pal = c3 + 16 * 12 * 16 * 16;  // [16,3,16]     768

  conv1_k<<<1536, 256, 0, stream>>>(x, w1, b1, c1);
  convs_k<32, 6><<<768, 256, 0, stream>>>(c1, w2, b2, c2, 12);
  convs_k<16, 12><<<192, 256, 0, stream>>>(c2, w3, b3, c3, 12);
  conv456_k<<<16, 256, 0, stream>>>(c3, w4, b4, w5, b5, w6, b6, pal);
  gather_k<<<dim3((HW / 4 + 255) / 256, 16), 256, 0, stream>>>(blog, pal, out);
}

// Round 6
// 325.223 us; speedup vs baseline: 1.1803x; 1.0068x over previous
//
#include <hip/hip_runtime.h>

#define HW 160000   // 400*400
#define WIMG 400

typedef float v4 __attribute__((ext_vector_type(4)));

// -------------------------------------------------------------------------
// conv1: x[B,3,400,400] -> leaky(conv 3->6, k3 s2 p1) restricted to out
// region [0..63]^2 (receptive field of the palette 4x4).
// out: c1[B,6,64,64]. 16*6*64*64 = 393216 threads. [verified R2/R4/R5]
// -------------------------------------------------------------------------
__global__ __launch_bounds__(256) void conv1_k(const float* __restrict__ x,
                                               const float* __restrict__ w,
                                               const float* __restrict__ bias,
                                               float* __restrict__ out) {
  int idx = blockIdx.x * 256 + threadIdx.x;
  int j = idx & 63;
  int i = (idx >> 6) & 63;
  int t = idx >> 12;
  int o = t % 6;
  int b = t / 6;
  float acc = bias[o];
#pragma unroll
  for (int c = 0; c < 3; c++) {
    const float* xc = x + (size_t)(b * 3 + c) * HW;
    const float* wc = w + (o * 3 + c) * 9;
#pragma unroll
    for (int di = 0; di < 3; di++) {
      int xi = 2 * i - 1 + di;
      if (xi < 0) continue;
#pragma unroll
      for (int dj = 0; dj < 3; dj++) {
        int xj = 2 * j - 1 + dj;
        if (xj < 0) continue;
        acc = fmaf(xc[xi * WIMG + xj], wc[di * 3 + dj], acc);
      }
    }
  }
  out[idx] = acc >= 0.f ? acc : 0.01f * acc;
}

// Generic strided 3x3 s2 p1 conv + leaky, flat-parallel, one thread/output.
// N = output spatial dim (input is 2N x 2N), CIN input channels. [verified]
template <int N, int CIN>
__global__ __launch_bounds__(256) void convs_k(const float* __restrict__ in,
                                               const float* __restrict__ w,
                                               const float* __restrict__ bias,
                                               float* __restrict__ out,
                                               int cout) {
  int idx = blockIdx.x * 256 + threadIdx.x;
  int j = idx & (N - 1);
  int i = (idx / N) & (N - 1);
  int t = idx / (N * N);
  int o = t % cout;
  int b = t / cout;
  float acc = bias[o];
#pragma unroll
  for (int c = 0; c < CIN; c++) {
    const float* xc = in + (size_t)(b * CIN + c) * (4 * N * N);
    const float* wc = w + (o * CIN + c) * 9;
#pragma unroll
    for (int di = 0; di < 3; di++) {
      int xi = 2 * i - 1 + di;
      if (xi < 0) continue;
#pragma unroll
      for (int dj = 0; dj < 3; dj++) {
        int xj = 2 * j - 1 + dj;
        if (xj < 0) continue;
        acc = fmaf(xc[xi * 2 * N + xj], wc[di * 3 + dj], acc);
      }
    }
  }
  out[idx] = acc >= 0.f ? acc : 0.01f * acc;
}

// -------------------------------------------------------------------------
// conv4+conv5+conv6 fused, one block per batch; c3[b] staged into LDS with
// coalesced loads (12/thread) so the 16-block kernel does not issue 324
// scattered global reads per thread. Stage logic identical to R1-verified.
// -------------------------------------------------------------------------
__global__ __launch_bounds__(256) void conv456_k(
    const float* __restrict__ c3, const float* __restrict__ w4,
    const float* __restrict__ b4, const float* __restrict__ w5,
    const float* __restrict__ b5, const float* __restrict__ w6,
    const float* __restrict__ b6, float* __restrict__ pal) {
  __shared__ float s3[3072];  // c3 tile: 12ch x 16x16
  __shared__ float s4[768];   // conv4 out: 12ch x 8x8
  __shared__ float s5[96];    // conv5 out: 6ch x 4x4, layout o*16 + (i*4+j)
  int tid = threadIdx.x;
  int b = blockIdx.x;
  const float* cb = c3 + (size_t)b * 3072;
#pragma unroll
  for (int r = 0; r < 12; r++) s3[tid + 256 * r] = cb[tid + 256 * r];
  __syncthreads();

  // conv4: 12x8x8, 3 outputs/thread
#pragma unroll
  for (int r = 0; r < 3; r++) {
    int idx = tid + 256 * r;
    int j = idx & 7, i = (idx >> 3) & 7, o = idx >> 6;
    float a = b4[o];
    for (int c = 0; c < 12; c++) {
      const float* wc = w4 + (o * 12 + c) * 9;
      const float* sc = s3 + c * 256;
#pragma unroll
      for (int di = 0; di < 3; di++) {
        int xi = 2 * i - 1 + di;
        if (xi < 0) continue;
#pragma unroll
        for (int dj = 0; dj < 3; dj++) {
          int xj = 2 * j - 1 + dj;
          if (xj < 0) continue;
          a = fmaf(sc[xi * 16 + xj], wc[di * 3 + dj], a);
        }
      }
    }
    s4[idx] = a >= 0.f ? a : 0.01f * a;
  }
  __syncthreads();

  // conv5: 6x4x4 on 96 threads
  if (tid < 96) {
    int j = tid & 3, i = (tid >> 2) & 3, o = tid >> 4;
    float a = b5[o];
    for (int c = 0; c < 12; c++) {
      const float* wc = w5 + (o * 12 + c) * 9;
      const float* sc = s4 + c * 64;
#pragma unroll
      for (int di = 0; di < 3; di++) {
        int xi = 2 * i - 1 + di;
        if (xi < 0) continue;
#pragma unroll
        for (int dj = 0; dj < 3; dj++) {
          int xj = 2 * j - 1 + dj;
          if (xj < 0) continue;
          a = fmaf(sc[xi * 8 + xj], wc[di * 3 + dj], a);
        }
      }
    }
    s5[tid] = a >= 0.f ? a : 0.01f * a;
  }
  __syncthreads();

  // conv6 (1x1) + relu -> pal[b,3,16]
  if (tid < 48) {
    int k = tid & 15, o = tid >> 4;
    float a = b6[o];
#pragma unroll
    for (int c = 0; c < 6; c++) a = fmaf(s5[c * 16 + k], w6[o * 6 + c], a);
    pal[b * 48 + o * 16 + k] = a > 0.f ? a : 0.f;
  }
}

// -------------------------------------------------------------------------
// gather: 8 px/thread, ALL 32 channel float4 NT loads hoisted (max MLP,
// halves per-pixel address/store overhead vs 4px), then streaming argmax
// tie-sum: greater -> reset RGB to pal[k]; equal -> add pal[k]. Exactly
// reproduces the reference (probs==max) one-hot-with-ties contraction
// (softmax monotone; prob ties <=> bitwise-equal fp32 logits).
// -------------------------------------------------------------------------
__global__ __launch_bounds__(256) void gather_k(const float* __restrict__ logits,
                                                const float* __restrict__ pal,
                                                float* __restrict__ out) {
  __shared__ float ps[48];
  int b = blockIdx.y;
  int tid = threadIdx.x;
  if (tid < 48) ps[tid] = pal[b * 48 + tid];
  __syncthreads();
  int q = blockIdx.x * 256 + tid;
  if (q >= HW / 8) return;
  const float* lg = logits + (size_t)b * 16 * HW + q * 8;

  v4 ta[16], tb[16];
#pragma unroll
  for (int k = 0; k < 16; k++) {
    const float* lk = lg + (size_t)k * HW;
    ta[k] = __builtin_nontemporal_load((const v4*)lk);
    tb[k] = __builtin_nontemporal_load((const v4*)(lk + 4));
  }

  float mx[8] = {ta[0].x, ta[0].y, ta[0].z, ta[0].w,
                 tb[0].x, tb[0].y, tb[0].z, tb[0].w};
  float p0 = ps[0], p1 = ps[16], p2 = ps[32];
  float r0[8], r1[8], r2[8];
#pragma unroll
  for (int pp = 0; pp < 8; pp++) { r0[pp] = p0; r1[pp] = p1; r2[pp] = p2; }

#pragma unroll
  for (int k = 1; k < 16; k++) {
    float q0 = ps[k], q1 = ps[16 + k], q2 = ps[32 + k];
    float vv[8] = {ta[k].x, ta[k].y, ta[k].z, ta[k].w,
                   tb[k].x, tb[k].y, tb[k].z, tb[k].w};
#pragma unroll
    for (int pp = 0; pp < 8; pp++) {
      float val = vv[pp];
      bool gt = val > mx[pp];
      bool ge = val >= mx[pp];
      mx[pp] = ge ? val : mx[pp];
      r0[pp] = (gt ? 0.f : r0[pp]) + (ge ? q0 : 0.f);
      r1[pp] = (gt ? 0.f : r1[pp]) + (ge ? q1 : 0.f);
      r2[pp] = (gt ? 0.f : r2[pp]) + (ge ? q2 : 0.f);
    }
  }
  float* ob = out + (size_t)b * 3 * HW + q * 8;
  v4 s0 = {r0[0], r0[1], r0[2], r0[3]}, s1 = {r0[4], r0[5], r0[6], r0[7]};
  v4 s2 = {r1[0], r1[1], r1[2], r1[3]}, s3 = {r1[4], r1[5], r1[6], r1[7]};
  v4 s4 = {r2[0], r2[1], r2[2], r2[3]}, s5 = {r2[4], r2[5], r2[6], r2[7]};
  __builtin_nontemporal_store(s0, (v4*)ob);
  __builtin_nontemporal_store(s1, (v4*)(ob + 4));
  __builtin_nontemporal_store(s2, (v4*)(ob + HW));
  __builtin_nontemporal_store(s3, (v4*)(ob + HW + 4));
  __builtin_nontemporal_store(s4, (v4*)(ob + 2 * HW));
  __builtin_nontemporal_store(s5, (v4*)(ob + 2 * HW + 4));
}

extern "C" void kernel_launch(void* const* d_in, const int* in_sizes, int n_in,
                              void* d_out, int out_size, void* d_ws, size_t ws_size,
                              hipStream_t stream) {
  const float* x    = (const float*)d_in[0];
  const float* blog = (const float*)d_in[1];
  const float* w1 = (const float*)d_in[2];
  const float* b1 = (const float*)d_in[3];
  const float* w2 = (const float*)d_in[4];
  const float* b2 = (const float*)d_in[5];
  const float* w3 = (const float*)d_in[6];
  const float* b3 = (const float*)d_in[7];
  const float* w4 = (const float*)d_in[8];
  const float* b4 = (const float*)d_in[9];
  const float* w5 = (const float*)d_in[10];
  const float* b5 = (const float*)d_in[11];
  const float* w6 = (const float*)d_in[12];
  const float* b6 = (const float*)d_in[13];
  float* out = (float*)d_out;

  float* c1  = (float*)d_ws;            // [16,6,64,64]  393216
  float* c2  = c1 + 16 * 6 * 64 * 64;   // [16,12,32,32] 196608
  float* c3  = c2 + 16 * 12 * 32 * 32;  // [16,12,16,16] 49152
  float* pal = c3 + 16 * 12 * 16 * 16;  // [16,3,16]     768

  conv1_k<<<1536, 256, 0, stream>>>(x, w1, b1, c1);
  convs_k<32, 6><<<768, 256, 0, stream>>>(c1, w2, b2, c2, 12);
  convs_k<16, 12><<<192, 256, 0, stream>>>(c2, w3, b3, c3, 12);
  conv456_k<<<16, 256, 0, stream>>>(c3, w4, b4, w5, b5, w6, b6, pal);
  gather_k<<<dim3((HW / 8 + 255) / 256, 16), 256, 0, stream>>>(blog, pal, out);
}